// Round 5
// baseline (382.824 us; speedup 1.0000x reference)
//
#include <hip/hip_runtime.h>
#include <math.h>

#define B_ 8
#define N_ 2048
#define D_ 512
#define NROWS (B_ * N_)   // 16384
#define HTS (NROWS + 32)  // padded Ht row stride (breaks 32KB L2 aliasing)
#define NEG_ALPHA 0.1f

typedef __bf16 bf16;
typedef __bf16 bf16x4 __attribute__((ext_vector_type(4)));
typedef __bf16 bf16x8 __attribute__((ext_vector_type(8)));
typedef float f32x4 __attribute__((ext_vector_type(4)));
typedef float f32x16 __attribute__((ext_vector_type(16)));

// ---------------------------------------------------------------------------
// k_prep_wa: Wt[dout][din] = bf16(W[din][dout]);  wa{1,2} = W @ a{1,2} (fp32)
// ---------------------------------------------------------------------------
__global__ __launch_bounds__(256) void k_prep_wa(const float* __restrict__ W,
                                                 const float* __restrict__ a1,
                                                 const float* __restrict__ a2,
                                                 bf16* __restrict__ Wt,
                                                 float* __restrict__ wa1,
                                                 float* __restrict__ wa2) {
  const int t = threadIdx.x;
  const int bid = blockIdx.x;
#pragma unroll
  for (int p = 0; p < 2; ++p) {
    int din = t + p * 256;
    Wt[bid * D_ + din] = (bf16)W[(size_t)din * D_ + bid];
  }
  if (bid < 128) {
    const int wv = t >> 6, lane = t & 63;
    const int row = bid * 4 + wv;
    const float* wr = W + (size_t)row * D_;
    float d1 = 0.f, d2 = 0.f;
#pragma unroll
    for (int p = 0; p < 8; ++p) {
      int c = lane + p * 64;
      float w = wr[c];
      d1 = fmaf(w, a1[c], d1);
      d2 = fmaf(w, a2[c], d2);
    }
#pragma unroll
    for (int off = 32; off > 0; off >>= 1) {
      d1 += __shfl_down(d1, off, 64);
      d2 += __shfl_down(d2, off, 64);
    }
    if (lane == 0) {
      wa1[row] = d1;
      wa2[row] = d2;
    }
  }
}

// ---------------------------------------------------------------------------
// k_scores_x: s1[r] = X[r,:].wa1 ; s2[r] = X[r,:].wa2 (fp32-exact logits)
// ---------------------------------------------------------------------------
__global__ __launch_bounds__(256) void k_scores_x(const float* __restrict__ X,
                                                  const float* __restrict__ wa1,
                                                  const float* __restrict__ wa2,
                                                  float* __restrict__ s1,
                                                  float* __restrict__ s2) {
  const int wv = threadIdx.x >> 6, lane = threadIdx.x & 63;
  const int r = blockIdx.x * 4 + wv;
  const float* x = X + (size_t)r * D_;
  float d1 = 0.f, d2 = 0.f;
#pragma unroll
  for (int p = 0; p < 2; ++p) {
    int c = lane * 4 + p * 256;
    float4 xv = *(const float4*)&x[c];
    float4 w1 = *(const float4*)&wa1[c];
    float4 w2 = *(const float4*)&wa2[c];
    d1 += xv.x * w1.x + xv.y * w1.y + xv.z * w1.z + xv.w * w1.w;
    d2 += xv.x * w2.x + xv.y * w2.y + xv.z * w2.z + xv.w * w2.w;
  }
#pragma unroll
  for (int off = 32; off > 0; off >>= 1) {
    d1 += __shfl_down(d1, off, 64);
    d2 += __shfl_down(d2, off, 64);
  }
  if (lane == 0) {
    s1[r] = d1;
    s2[r] = d2;
  }
}

// ---------------------------------------------------------------------------
// k_hiddenT: Ht[dout][row] = bf16(sum_din Wt[dout][din] * X[row][din])
// BM=BN=128, BK=32, 16x16x32 MFMA. Double-buffered LDS -> ONE barrier/iter,
// depth-1 register prefetch of global operands.
// ---------------------------------------------------------------------------
#define LDH 40

__global__ __launch_bounds__(256, 2) void k_hiddenT(const float* __restrict__ X,
                                                    const bf16* __restrict__ Wt,
                                                    bf16* __restrict__ Ht) {
  __shared__ bf16 As[2][128][LDH];
  __shared__ bf16 Bs[2][128][LDH];
  const int t = threadIdx.x;
  const int m0 = blockIdx.y * 128;
  const int n0 = blockIdx.x * 128;
  const int lane = t & 63, w = t >> 6;
  const int wm = w >> 1, wn = w & 1;
  const int l15 = lane & 15, q = lane >> 4;

  f32x4 acc[4][4];
#pragma unroll
  for (int i = 0; i < 4; ++i)
#pragma unroll
    for (int j = 0; j < 4; ++j) acc[i][j] = (f32x4){0.f, 0.f, 0.f, 0.f};

  bf16x8 av[2];
  float4 bv[4];
#pragma unroll
  for (int p = 0; p < 2; ++p) {
    int s = t + p * 256;
    av[p] = *(const bf16x8*)&Wt[(size_t)(m0 + (s >> 2)) * D_ + (s & 3) * 8];
  }
#pragma unroll
  for (int p = 0; p < 4; ++p) {
    int s = t + p * 256;
    bv[p] = *(const float4*)&X[(size_t)(n0 + (s >> 3)) * D_ + (s & 7) * 4];
  }

#pragma unroll
  for (int it = 0; it < D_ / 32; ++it) {
    const int k0 = it * 32;
    const int buf = it & 1;
#pragma unroll
    for (int p = 0; p < 2; ++p) {
      int s = t + p * 256;
      *(bf16x8*)&As[buf][s >> 2][(s & 3) * 8] = av[p];
    }
#pragma unroll
    for (int p = 0; p < 4; ++p) {
      int s = t + p * 256;
      float4 v = bv[p];
      bf16x4 h = {(bf16)v.x, (bf16)v.y, (bf16)v.z, (bf16)v.w};
      *(bf16x4*)&Bs[buf][s >> 3][(s & 7) * 4] = h;
    }
    __syncthreads();
    if (k0 + 32 < D_) {
#pragma unroll
      for (int p = 0; p < 2; ++p) {
        int s = t + p * 256;
        av[p] = *(const bf16x8*)&Wt[(size_t)(m0 + (s >> 2)) * D_ + k0 + 32 + (s & 3) * 8];
      }
#pragma unroll
      for (int p = 0; p < 4; ++p) {
        int s = t + p * 256;
        bv[p] = *(const float4*)&X[(size_t)(n0 + (s >> 3)) * D_ + k0 + 32 + (s & 7) * 4];
      }
    }
    bf16x8 a[4], bb[4];
#pragma unroll
    for (int i = 0; i < 4; ++i)
      a[i] = *(const bf16x8*)&As[buf][wm * 64 + i * 16 + l15][q * 8];
#pragma unroll
    for (int j = 0; j < 4; ++j)
      bb[j] = *(const bf16x8*)&Bs[buf][wn * 64 + j * 16 + l15][q * 8];
#pragma unroll
    for (int i = 0; i < 4; ++i)
#pragma unroll
      for (int j = 0; j < 4; ++j)
        acc[i][j] =
            __builtin_amdgcn_mfma_f32_16x16x32_bf16(a[i], bb[j], acc[i][j], 0, 0, 0);
  }
#pragma unroll
  for (int i = 0; i < 4; ++i)
#pragma unroll
    for (int r = 0; r < 4; ++r) {
      int dout = m0 + wm * 64 + i * 16 + q * 4 + r;
#pragma unroll
      for (int j = 0; j < 4; ++j) {
        int row = n0 + wn * 64 + j * 16 + l15;
        Ht[(size_t)dout * HTS + row] = (bf16)acc[i][j][r];
      }
    }
}

// ---------------------------------------------------------------------------
// k_attn: out = elu( softmax_row(mask(leaky(s1_i+s2_j))) @ H )
// 64 rows x 512 d per block; 8 waves each own 64 d. BK=128, 16 chunks, one
// barrier per chunk. B-fragments (Ht) depth-1 prefetched global->VGPR,
// DOUBLE-BUFFERED so the MFMA phase touches only registers + Ps LDS. The
// compiler's vmcnt(0) drain at the barrier lands ~a full chunk after issue.
// ---------------------------------------------------------------------------
#define AT_BM 64
#define AT_BK 128
#define NCHUNK (N_ / AT_BK)  // 16
#define LDPS 136             // Ps row stride (bf16): 272 B, 16B-aligned

__global__ __launch_bounds__(512, 2) void k_attn(const bf16* __restrict__ Ht,
                                                 const int* __restrict__ graph,
                                                 const float* __restrict__ s1,
                                                 const float* __restrict__ s2,
                                                 float* __restrict__ out) {
  __shared__ bf16 Ps[2][AT_BM][LDPS];   // 34.8 KB
  __shared__ float s2s[N_];             // 8 KB
  __shared__ float sum_part[AT_BM][8];  // 2 KB
  __shared__ float row_sum[AT_BM];

  const int t = threadIdx.x;
  const int b = blockIdx.y;
  const int i0 = blockIdx.x * AT_BM;
  const int lane = t & 63, w = t >> 6;
  const int r31 = lane & 31, half = lane >> 5;
  const int d0 = w * 64;

  const bf16* Htb = Ht + (size_t)b * N_;  // Htb[d*HTS + j]
  const int* Gb = graph + ((size_t)b * N_ + i0) * N_;

  for (int c = t; c < N_; c += 512) s2s[c] = s2[b * N_ + c];

  const int pi = t >> 3;        // P row 0..63
  const int pj = (t & 7) * 16;  // 16 j-values per thread
  const float s1r = s1[b * N_ + i0 + pi];
  float rsum = 0.f;

  f32x16 acc[2][2];
#pragma unroll
  for (int i = 0; i < 2; ++i)
#pragma unroll
    for (int j = 0; j < 2; ++j)
#pragma unroll
      for (int r = 0; r < 16; ++r) acc[i][j][r] = 0.f;

  // prefetch buffers
  int gg[16];
  bf16x8 bp[2][16];  // [parity][ks*2 + {lo,hi}] B-fragments for one chunk

  // chunk-0 graph
#pragma unroll
  for (int u = 0; u < 4; ++u)
    *(int4*)&gg[u * 4] = *(const int4*)&Gb[(size_t)pi * N_ + pj + u * 4];
  // chunk-0 B-fragments
#pragma unroll
  for (int ks = 0; ks < 8; ++ks) {
    const int ko = ks * 16 + half * 8;
    bp[0][ks * 2 + 0] = *(const bf16x8*)&Htb[(size_t)(d0 + r31) * HTS + ko];
    bp[0][ks * 2 + 1] = *(const bf16x8*)&Htb[(size_t)(d0 + 32 + r31) * HTS + ko];
  }

  __syncthreads();  // s2s ready

  float pv[16];
#pragma unroll
  for (int u = 0; u < 16; ++u) {
    float e = s1r + s2s[pj + u];
    e = (e > 0.f) ? e : NEG_ALPHA * e;
    float pe = (gg[u] != 0) ? __expf(e) : 0.f;
    pv[u] = pe;
    rsum += pe;
  }

#pragma unroll
  for (int p = 0; p < NCHUNK; ++p) {
    const int j0 = p * AT_BK;
    const int cur = p & 1, nxt = cur ^ 1;
    // publish P chunk p
    {
      bf16x8 w0 = {(bf16)pv[0], (bf16)pv[1], (bf16)pv[2], (bf16)pv[3],
                   (bf16)pv[4], (bf16)pv[5], (bf16)pv[6], (bf16)pv[7]};
      bf16x8 w1 = {(bf16)pv[8],  (bf16)pv[9],  (bf16)pv[10], (bf16)pv[11],
                   (bf16)pv[12], (bf16)pv[13], (bf16)pv[14], (bf16)pv[15]};
      *(bf16x8*)&Ps[cur][pi][pj] = w0;
      *(bf16x8*)&Ps[cur][pi][pj + 8] = w1;
    }
    // graph prefetch chunk p+1
    if (p + 1 < NCHUNK) {
#pragma unroll
      for (int u = 0; u < 4; ++u)
        *(int4*)&gg[u * 4] =
            *(const int4*)&Gb[(size_t)pi * N_ + j0 + AT_BK + pj + u * 4];
    }
    __syncthreads();  // Ps[cur] visible (also drains the p-1-issued B loads)
    // B prefetch chunk p+1: issue immediately, consumed after NEXT barrier
    if (p + 1 < NCHUNK) {
#pragma unroll
      for (int ks = 0; ks < 8; ++ks) {
        const int ko = ks * 16 + half * 8;
        bp[nxt][ks * 2 + 0] =
            *(const bf16x8*)&Htb[(size_t)(d0 + r31) * HTS + j0 + AT_BK + ko];
        bp[nxt][ks * 2 + 1] =
            *(const bf16x8*)&Htb[(size_t)(d0 + 32 + r31) * HTS + j0 + AT_BK + ko];
      }
    }
    // MFMA phase: registers + Ps LDS only
#pragma unroll
    for (int ks = 0; ks < 8; ++ks) {
      const int ko = ks * 16 + half * 8;
      bf16x8 a0 = *(const bf16x8*)&Ps[cur][r31][ko];
      bf16x8 a1 = *(const bf16x8*)&Ps[cur][32 + r31][ko];
      bf16x8 b0 = bp[cur][ks * 2 + 0];
      bf16x8 b1 = bp[cur][ks * 2 + 1];
      acc[0][0] = __builtin_amdgcn_mfma_f32_32x32x16_bf16(a0, b0, acc[0][0], 0, 0, 0);
      acc[0][1] = __builtin_amdgcn_mfma_f32_32x32x16_bf16(a0, b1, acc[0][1], 0, 0, 0);
      acc[1][0] = __builtin_amdgcn_mfma_f32_32x32x16_bf16(a1, b0, acc[1][0], 0, 0, 0);
      acc[1][1] = __builtin_amdgcn_mfma_f32_32x32x16_bf16(a1, b1, acc[1][1], 0, 0, 0);
    }
    // exp for chunk p+1 in the MFMA shadow
    if (p + 1 < NCHUNK) {
#pragma unroll
      for (int u = 0; u < 16; ++u) {
        float e = s1r + s2s[j0 + AT_BK + pj + u];
        e = (e > 0.f) ? e : NEG_ALPHA * e;
        float pe = (gg[u] != 0) ? __expf(e) : 0.f;
        pv[u] = pe;
        rsum += pe;
      }
    }
  }

  // row sums
  sum_part[pi][t & 7] = rsum;
  __syncthreads();
  if (t < AT_BM) {
    float s = 0.f;
#pragma unroll
    for (int k = 0; k < 8; ++k) s += sum_part[t][k];
    row_sum[t] = s;
  }
  __syncthreads();

  // epilogue: normalize + elu + store
  // C/D (32x32): col = lane&31, row = (r&3) + 8*(r>>2) + 4*half
#pragma unroll
  for (int mt = 0; mt < 2; ++mt) {
    float inv[16];
#pragma unroll
    for (int r = 0; r < 16; ++r)
      inv[r] = 1.f / row_sum[mt * 32 + (r & 3) + 8 * (r >> 2) + 4 * half];
#pragma unroll
    for (int nt = 0; nt < 2; ++nt) {
      const int d = d0 + nt * 32 + r31;
#pragma unroll
      for (int r = 0; r < 16; ++r) {
        int i = mt * 32 + (r & 3) + 8 * (r >> 2) + 4 * half;
        float x = acc[mt][nt][r] * inv[r];
        out[((size_t)b * N_ + i0 + i) * D_ + d] = (x > 0.f) ? x : expm1f(x);
      }
    }
  }
}

// ---------------------------------------------------------------------------
extern "C" void kernel_launch(void* const* d_in, const int* in_sizes, int n_in,
                              void* d_out, int out_size, void* d_ws,
                              size_t ws_size, hipStream_t stream) {
  const float* X = (const float*)d_in[0];
  const int* graph = (const int*)d_in[1];
  const float* W = (const float*)d_in[2];
  const float* a1 = (const float*)d_in[3];
  const float* a2 = (const float*)d_in[4];
  float* out = (float*)d_out;

  char* ws = (char*)d_ws;
  bf16* Wt = (bf16*)ws;                // 512 KB
  bf16* Ht = (bf16*)(ws + (1 << 19));  // 512*HTS*2 ~= 16.03 MB
  float* s1 = (float*)(ws + (1 << 19) + (size_t)D_ * HTS * 2);
  float* s2 = s1 + NROWS;
  float* wa1 = s2 + NROWS;
  float* wa2 = wa1 + D_;

  hipLaunchKernelGGL(k_prep_wa, dim3(512), dim3(256), 0, stream, W, a1, a2, Wt,
                     wa1, wa2);
  hipLaunchKernelGGL(k_scores_x, dim3(NROWS / 4), dim3(256), 0, stream, X, wa1,
                     wa2, s1, s2);
  hipLaunchKernelGGL(k_hiddenT, dim3(NROWS / 128, D_ / 128), dim3(256), 0,
                     stream, X, Wt, Ht);
  hipLaunchKernelGGL(k_attn, dim3(N_ / AT_BM, B_), dim3(512), 0, stream, Ht,
                     graph, s1, s2, out);
}

// Round 6
// 366.369 us; speedup vs baseline: 1.0449x; 1.0449x over previous
//
#include <hip/hip_runtime.h>
#include <math.h>

#define B_ 8
#define N_ 2048
#define D_ 512
#define NROWS (B_ * N_)   // 16384
#define HTS (NROWS + 32)  // padded Ht row stride
#define NEG_ALPHA 0.1f

typedef __bf16 bf16;
typedef __bf16 bf16x4 __attribute__((ext_vector_type(4)));
typedef __bf16 bf16x8 __attribute__((ext_vector_type(8)));
typedef float f32x4 __attribute__((ext_vector_type(4)));
typedef float f32x16 __attribute__((ext_vector_type(16)));

// async global->LDS DMA, 16 B per lane, dest = wave-uniform base + lane*16
__device__ __forceinline__ void async_copy16(const void* g, void* l) {
  __builtin_amdgcn_global_load_lds(
      (const __attribute__((address_space(1))) void*)g,
      (__attribute__((address_space(3))) void*)l, 16, 0, 0);
}

// ---------------------------------------------------------------------------
// k_prep_wa: Wt[dout][din] = bf16(W[din][dout]);  wa{1,2} = W @ a{1,2} (fp32)
// ---------------------------------------------------------------------------
__global__ __launch_bounds__(256) void k_prep_wa(const float* __restrict__ W,
                                                 const float* __restrict__ a1,
                                                 const float* __restrict__ a2,
                                                 bf16* __restrict__ Wt,
                                                 float* __restrict__ wa1,
                                                 float* __restrict__ wa2) {
  const int t = threadIdx.x;
  const int bid = blockIdx.x;
#pragma unroll
  for (int p = 0; p < 2; ++p) {
    int din = t + p * 256;
    Wt[bid * D_ + din] = (bf16)W[(size_t)din * D_ + bid];
  }
  if (bid < 128) {
    const int wv = t >> 6, lane = t & 63;
    const int row = bid * 4 + wv;
    const float* wr = W + (size_t)row * D_;
    float d1 = 0.f, d2 = 0.f;
#pragma unroll
    for (int p = 0; p < 8; ++p) {
      int c = lane + p * 64;
      float w = wr[c];
      d1 = fmaf(w, a1[c], d1);
      d2 = fmaf(w, a2[c], d2);
    }
#pragma unroll
    for (int off = 32; off > 0; off >>= 1) {
      d1 += __shfl_down(d1, off, 64);
      d2 += __shfl_down(d2, off, 64);
    }
    if (lane == 0) {
      wa1[row] = d1;
      wa2[row] = d2;
    }
  }
}

// ---------------------------------------------------------------------------
// k_conv_scores: Xb = bf16(X) (row-major) ; s1 = X.wa1 ; s2 = X.wa2 (fp32)
// One wave per row; X read exactly once.
// ---------------------------------------------------------------------------
__global__ __launch_bounds__(256) void k_conv_scores(
    const float* __restrict__ X, const float* __restrict__ wa1,
    const float* __restrict__ wa2, bf16* __restrict__ Xb,
    float* __restrict__ s1, float* __restrict__ s2) {
  __shared__ float was1[D_], was2[D_];
  const int t = threadIdx.x;
  for (int c = t; c < D_; c += 256) {
    was1[c] = wa1[c];
    was2[c] = wa2[c];
  }
  __syncthreads();
  const int wv = t >> 6, lane = t & 63;
  const int r = blockIdx.x * 4 + wv;
  const float* x = X + (size_t)r * D_;
  float d1 = 0.f, d2 = 0.f;
#pragma unroll
  for (int p = 0; p < 2; ++p) {
    int c = lane * 4 + p * 256;
    float4 xv = *(const float4*)&x[c];
    bf16x4 xb = {(bf16)xv.x, (bf16)xv.y, (bf16)xv.z, (bf16)xv.w};
    *(bf16x4*)&Xb[(size_t)r * D_ + c] = xb;
    d1 += xv.x * was1[c] + xv.y * was1[c + 1] + xv.z * was1[c + 2] +
          xv.w * was1[c + 3];
    d2 += xv.x * was2[c] + xv.y * was2[c + 1] + xv.z * was2[c + 2] +
          xv.w * was2[c + 3];
  }
#pragma unroll
  for (int off = 32; off > 0; off >>= 1) {
    d1 += __shfl_down(d1, off, 64);
    d2 += __shfl_down(d2, off, 64);
  }
  if (lane == 0) {
    s1[r] = d1;
    s2[r] = d2;
  }
}

// ---------------------------------------------------------------------------
// k_hiddenT: Ht[dout][row] = bf16(sum_din Wt[dout][din] * Xb[row][din])
// BM=128 dout x BN=128 row, BK=32, 256 thr / 4 waves, 32x32x16 MFMA.
// Async DMA staging (global_load_lds x16), double-buffered, 1 barrier/iter.
// LDS granule swizzle pc = c ^ (r&3) ^ ((r>>2)&3) -> 2-way banks (free).
// ---------------------------------------------------------------------------
__global__ __launch_bounds__(256, 4) void k_hiddenT(const bf16* __restrict__ Xb,
                                                    const bf16* __restrict__ Wt,
                                                    bf16* __restrict__ Ht) {
  __shared__ bf16 As[2][128 * 32];  // 8 KB each, swizzled granules
  __shared__ bf16 Bs[2][128 * 32];
  const int t = threadIdx.x;
  const int m0 = blockIdx.y * 128;  // dout
  const int n0 = blockIdx.x * 128;  // row
  const int lane = t & 63, w = t >> 6;
  const int wm = w >> 1, wn = w & 1;
  const int r31 = lane & 31, half = lane >> 5;

  const char* WtB = (const char*)Wt;
  const char* XbB = (const char*)Xb;

  // per-lane DMA source byte offsets (k0-independent)
  int srcA[2], srcB[2];
#pragma unroll
  for (int q = 0; q < 2; ++q) {
    int g = (w * 2 + q) * 64 + lane;
    int r = g >> 2, pc = g & 3;
    int c = pc ^ (r & 3) ^ ((r >> 2) & 3);
    srcA[q] = ((m0 + r) * D_ + c * 8) * 2;
    srcB[q] = ((n0 + r) * D_ + c * 8) * 2;
  }

  f32x16 acc[2][2];
#pragma unroll
  for (int i = 0; i < 2; ++i)
#pragma unroll
    for (int j = 0; j < 2; ++j)
#pragma unroll
      for (int r = 0; r < 16; ++r) acc[i][j][r] = 0.f;

  // DMA iter 0
#pragma unroll
  for (int q = 0; q < 2; ++q) {
    async_copy16(WtB + srcA[q], (char*)&As[0][0] + (w * 2 + q) * 1024);
    async_copy16(XbB + srcB[q], (char*)&Bs[0][0] + (w * 2 + q) * 1024);
  }

#pragma unroll
  for (int it = 0; it < D_ / 32; ++it) {
    const int cur = it & 1;
    __syncthreads();  // drains DMA(it); prior readers of buffers done
    if (it + 1 < D_ / 32) {
      const int koff = (it + 1) * 64;  // bytes for k0 step of 32 bf16
#pragma unroll
      for (int q = 0; q < 2; ++q) {
        async_copy16(WtB + srcA[q] + koff,
                     (char*)&As[cur ^ 1][0] + (w * 2 + q) * 1024);
        async_copy16(XbB + srcB[q] + koff,
                     (char*)&Bs[cur ^ 1][0] + (w * 2 + q) * 1024);
      }
    }
#pragma unroll
    for (int ks = 0; ks < 2; ++ks) {
      const int ko = ks * 16 + half * 8;
      const int c = ko >> 3;
      int mA = wm * 64 + r31, mB = wm * 64 + 32 + r31;
      int nA = wn * 64 + r31, nB = wn * 64 + 32 + r31;
      int pmA = c ^ (mA & 3) ^ ((mA >> 2) & 3);
      int pmB = c ^ (mB & 3) ^ ((mB >> 2) & 3);
      int pnA = c ^ (nA & 3) ^ ((nA >> 2) & 3);
      int pnB = c ^ (nB & 3) ^ ((nB >> 2) & 3);
      bf16x8 a0 = *(const bf16x8*)((const char*)&As[cur][0] + mA * 64 + pmA * 16);
      bf16x8 a1 = *(const bf16x8*)((const char*)&As[cur][0] + mB * 64 + pmB * 16);
      bf16x8 b0 = *(const bf16x8*)((const char*)&Bs[cur][0] + nA * 64 + pnA * 16);
      bf16x8 b1 = *(const bf16x8*)((const char*)&Bs[cur][0] + nB * 64 + pnB * 16);
      acc[0][0] = __builtin_amdgcn_mfma_f32_32x32x16_bf16(a0, b0, acc[0][0], 0, 0, 0);
      acc[0][1] = __builtin_amdgcn_mfma_f32_32x32x16_bf16(a0, b1, acc[0][1], 0, 0, 0);
      acc[1][0] = __builtin_amdgcn_mfma_f32_32x32x16_bf16(a1, b0, acc[1][0], 0, 0, 0);
      acc[1][1] = __builtin_amdgcn_mfma_f32_32x32x16_bf16(a1, b1, acc[1][1], 0, 0, 0);
    }
  }

  // epilogue: C/D 32x32: col(lane&31)=row-idx n, rowreg=(r&3)+8*(r>>2)+4*half=dout m
#pragma unroll
  for (int mt = 0; mt < 2; ++mt)
#pragma unroll
    for (int r = 0; r < 16; ++r) {
      int m = wm * 64 + mt * 32 + (r & 3) + 8 * (r >> 2) + 4 * half;
#pragma unroll
      for (int nt = 0; nt < 2; ++nt) {
        int n = wn * 64 + nt * 32 + r31;
        Ht[(size_t)(m0 + m) * HTS + n0 + n] = (bf16)acc[mt][nt][r];
      }
    }
}

// ---------------------------------------------------------------------------
// k_attn: out = elu( softmax_row(mask(leaky(s1_i+s2_j))) @ H )
// Block: 64 rows x 512 d (8 waves x 64 d). BK=32, 64 chunks, 1 barrier/chunk.
// Hs (512d x 32j bf16, swizzled) staged by async DMA, double-buffered; DMA
// for p+1 issued AFTER barrier p so the pre-barrier vmcnt(0) drain only waits
// on loads that have had a full chunk in flight. graph/s2 reg-prefetch depth 2.
// exp + Ps pack in the MFMA shadow. No max pass needed (|e|<~30; masked = 0).
// ---------------------------------------------------------------------------
#define AT_BM 64
#define AT_BK 32
#define NCH (N_ / AT_BK)  // 64
#define PS_S 40           // Ps row stride (bf16) = 80 B

__global__ __launch_bounds__(512, 4) void k_attn(const bf16* __restrict__ Ht,
                                                 const int* __restrict__ graph,
                                                 const float* __restrict__ s1,
                                                 const float* __restrict__ s2,
                                                 float* __restrict__ out) {
  __shared__ bf16 Hs[2][D_ * AT_BK];   // 32 KB each
  __shared__ bf16 Ps[2][AT_BM][PS_S];  // 5 KB each
  __shared__ float sum_part[AT_BM][8];
  __shared__ float row_sum[AT_BM];

  const int t = threadIdx.x;
  const int b = blockIdx.y;
  const int i0 = blockIdx.x * AT_BM;
  const int lane = t & 63, w = t >> 6;
  const int r31 = lane & 31, half = lane >> 5;
  const int d0 = w * 64;

  const char* HtB = (const char*)(Ht + (size_t)b * N_);
  const int* Gb = graph + ((size_t)b * N_ + i0) * N_;
  const float* s2g = s2 + b * N_;

  const int pi = t >> 3;       // P row 0..63
  const int pj = (t & 7) * 4;  // 4 j per thread per chunk
  const float s1r = s1[b * N_ + i0 + pi];
  float rsum = 0.f;

  f32x16 acc[2][2];
#pragma unroll
  for (int i = 0; i < 2; ++i)
#pragma unroll
    for (int j = 0; j < 2; ++j)
#pragma unroll
      for (int r = 0; r < 16; ++r) acc[i][j][r] = 0.f;

  // per-lane DMA source byte offsets (j0-independent)
  int dsrc[4];
#pragma unroll
  for (int q = 0; q < 4; ++q) {
    int g = (w * 4 + q) * 64 + lane;
    int d = g >> 2, pc = g & 3;
    int c = pc ^ (d & 3) ^ ((d >> 2) & 3);
    dsrc[q] = d * (HTS * 2) + c * 16;
  }

  // depth-2 register prefetch of graph + s2 (chunks 0 and 1)
  int4 gg[2];
  float4 sv[2];
  gg[0] = *(const int4*)&Gb[(size_t)pi * N_ + pj];
  sv[0] = *(const float4*)&s2g[pj];
  gg[1] = *(const int4*)&Gb[(size_t)pi * N_ + 32 + pj];
  sv[1] = *(const float4*)&s2g[32 + pj];
  // DMA chunk 0
#pragma unroll
  for (int q = 0; q < 4; ++q)
    async_copy16(HtB + dsrc[q], (char*)&Hs[0][0] + (w * 4 + q) * 1024);

  float pv[4];
  {
    int gA[4] = {gg[0].x, gg[0].y, gg[0].z, gg[0].w};
    float sA[4] = {sv[0].x, sv[0].y, sv[0].z, sv[0].w};
#pragma unroll
    for (int u = 0; u < 4; ++u) {
      float e = s1r + sA[u];
      e = (e > 0.f) ? e : NEG_ALPHA * e;
      pv[u] = (gA[u] != 0) ? __expf(e) : 0.f;
      rsum += pv[u];
    }
  }

#pragma unroll 2
  for (int p = 0; p < NCH; ++p) {
    const int cur = p & 1;
    const int j0 = p * AT_BK;
    // publish P chunk p (prev readers of this buffer finished before B_{p-1})
    {
      bf16x4 pb = {(bf16)pv[0], (bf16)pv[1], (bf16)pv[2], (bf16)pv[3]};
      *(bf16x4*)&Ps[cur][pi][pj] = pb;
    }
    __syncthreads();  // drains DMA(p) -> Hs[cur] valid; Ps[cur] visible
    if (p + 2 < NCH) {  // graph/s2 for chunk p+2 into the slot freed by pv(p)
      gg[cur] = *(const int4*)&Gb[(size_t)pi * N_ + j0 + 64 + pj];
      sv[cur] = *(const float4*)&s2g[j0 + 64 + pj];
    }
    if (p + 1 < NCH) {  // DMA chunk p+1 (flies across the MFMA phase)
#pragma unroll
      for (int q = 0; q < 4; ++q)
        async_copy16(HtB + dsrc[q] + (j0 + AT_BK) * 2,
                     (char*)&Hs[cur ^ 1][0] + (w * 4 + q) * 1024);
    }
    // MFMA phase: Ps + swizzled Hs reads only
#pragma unroll
    for (int ks = 0; ks < 2; ++ks) {
      const int ko = ks * 16 + half * 8;
      const int c = ko >> 3;
      int dA = d0 + r31, dB = d0 + 32 + r31;
      int pA = c ^ (dA & 3) ^ ((dA >> 2) & 3);
      int pB = c ^ (dB & 3) ^ ((dB >> 2) & 3);
      bf16x8 a0 = *(const bf16x8*)&Ps[cur][r31][ko];
      bf16x8 a1 = *(const bf16x8*)&Ps[cur][32 + r31][ko];
      bf16x8 b0 = *(const bf16x8*)((const char*)&Hs[cur][0] + dA * 64 + pA * 16);
      bf16x8 b1 = *(const bf16x8*)((const char*)&Hs[cur][0] + dB * 64 + pB * 16);
      acc[0][0] = __builtin_amdgcn_mfma_f32_32x32x16_bf16(a0, b0, acc[0][0], 0, 0, 0);
      acc[0][1] = __builtin_amdgcn_mfma_f32_32x32x16_bf16(a0, b1, acc[0][1], 0, 0, 0);
      acc[1][0] = __builtin_amdgcn_mfma_f32_32x32x16_bf16(a1, b0, acc[1][0], 0, 0, 0);
      acc[1][1] = __builtin_amdgcn_mfma_f32_32x32x16_bf16(a1, b1, acc[1][1], 0, 0, 0);
    }
    // exp for chunk p+1 in the MFMA shadow (gg loaded 2 chunks ago: already
    // drained by the barrier -> no vm wait here)
    if (p + 1 < NCH) {
      const int nx = cur ^ 1;
      int gA[4] = {gg[nx].x, gg[nx].y, gg[nx].z, gg[nx].w};
      float sA[4] = {sv[nx].x, sv[nx].y, sv[nx].z, sv[nx].w};
#pragma unroll
      for (int u = 0; u < 4; ++u) {
        float e = s1r + sA[u];
        e = (e > 0.f) ? e : NEG_ALPHA * e;
        pv[u] = (gA[u] != 0) ? __expf(e) : 0.f;
        rsum += pv[u];
      }
    }
  }

  // row sums
  sum_part[pi][t & 7] = rsum;
  __syncthreads();
  if (t < AT_BM) {
    float s = 0.f;
#pragma unroll
    for (int k = 0; k < 8; ++k) s += sum_part[t][k];
    row_sum[t] = s;
  }
  __syncthreads();

  // epilogue: normalize + elu + store
#pragma unroll
  for (int mt = 0; mt < 2; ++mt) {
    float inv[16];
#pragma unroll
    for (int r = 0; r < 16; ++r)
      inv[r] = 1.f / row_sum[mt * 32 + (r & 3) + 8 * (r >> 2) + 4 * half];
#pragma unroll
    for (int nt = 0; nt < 2; ++nt) {
      const int d = d0 + nt * 32 + r31;
#pragma unroll
      for (int r = 0; r < 16; ++r) {
        int i = mt * 32 + (r & 3) + 8 * (r >> 2) + 4 * half;
        float x = acc[mt][nt][r] * inv[r];
        out[((size_t)b * N_ + i0 + i) * D_ + d] = (x > 0.f) ? x : expm1f(x);
      }
    }
  }
}

// ---------------------------------------------------------------------------
extern "C" void kernel_launch(void* const* d_in, const int* in_sizes, int n_in,
                              void* d_out, int out_size, void* d_ws,
                              size_t ws_size, hipStream_t stream) {
  const float* X = (const float*)d_in[0];
  const int* graph = (const int*)d_in[1];
  const float* W = (const float*)d_in[2];
  const float* a1 = (const float*)d_in[3];
  const float* a2 = (const float*)d_in[4];
  float* out = (float*)d_out;

  char* ws = (char*)d_ws;
  bf16* Wt = (bf16*)ws;                            // 512 KB
  bf16* Ht = (bf16*)(ws + (1 << 19));              // 512*HTS*2 = 16,809,984 B
  bf16* Xb = (bf16*)(ws + 17334272);               // 16 MB
  float* s1 = (float*)(ws + 34111488);             // 64 KB
  float* s2 = (float*)(ws + 34177024);             // 64 KB
  float* wa1 = (float*)(ws + 34242560);            // 2 KB
  float* wa2 = (float*)(ws + 34244608);            // 2 KB

  hipLaunchKernelGGL(k_prep_wa, dim3(512), dim3(256), 0, stream, W, a1, a2, Wt,
                     wa1, wa2);
  hipLaunchKernelGGL(k_conv_scores, dim3(NROWS / 4), dim3(256), 0, stream, X,
                     wa1, wa2, Xb, s1, s2);
  hipLaunchKernelGGL(k_hiddenT, dim3(NROWS / 128, D_ / 128), dim3(256), 0,
                     stream, Xb, Wt, Ht);
  hipLaunchKernelGGL(k_attn, dim3(N_ / AT_BM, B_), dim3(512), 0, stream, Ht,
                     graph, s1, s2, out);
}

// Round 7
// 305.428 us; speedup vs baseline: 1.2534x; 1.1995x over previous
//
#include <hip/hip_runtime.h>
#include <math.h>

#define B_ 8
#define N_ 2048
#define D_ 512
#define NROWS (B_ * N_)   // 16384
#define HTS (NROWS + 32)  // padded Ht row stride
#define NEG_ALPHA 0.1f

typedef __bf16 bf16;
typedef __bf16 bf16x4 __attribute__((ext_vector_type(4)));
typedef __bf16 bf16x8 __attribute__((ext_vector_type(8)));
typedef float f32x4 __attribute__((ext_vector_type(4)));
typedef float f32x16 __attribute__((ext_vector_type(16)));

// async global->LDS DMA, 16 B per lane, dest = wave-uniform base + lane*16
__device__ __forceinline__ void async_copy16(const void* g, void* l) {
  __builtin_amdgcn_global_load_lds(
      (const __attribute__((address_space(1))) void*)g,
      (__attribute__((address_space(3))) void*)l, 16, 0, 0);
}
// s_waitcnt vmcnt(N), lgkm/exp unaffected. gfx9 imm: vm[3:0]|exp[6:4]|lgkm[11:8]|vm[15:14]
#define WAITVM4()  __builtin_amdgcn_s_waitcnt(0x0F74)
#define WAITVM20() __builtin_amdgcn_s_waitcnt(0x4F74)

// ---------------------------------------------------------------------------
// k_prep: LDS-tiled transpose Wt[dout][din] = bf16(W[din][dout])
// ---------------------------------------------------------------------------
__global__ __launch_bounds__(256) void k_prep(const float* __restrict__ W,
                                              bf16* __restrict__ Wt) {
  __shared__ float tile[64][65];
  const int bx = blockIdx.x & 7, by = blockIdx.x >> 3;
  const int dout0 = bx * 64, din0 = by * 64;
  const int r = threadIdx.x >> 4;   // 0..15
  const int c4 = threadIdx.x & 15;  // float4 col
#pragma unroll
  for (int p = 0; p < 4; ++p) {
    int rr = r + p * 16;
    float4 v = *(const float4*)&W[(size_t)(din0 + rr) * D_ + dout0 + c4 * 4];
    tile[rr][c4 * 4 + 0] = v.x;
    tile[rr][c4 * 4 + 1] = v.y;
    tile[rr][c4 * 4 + 2] = v.z;
    tile[rr][c4 * 4 + 3] = v.w;
  }
  __syncthreads();
#pragma unroll
  for (int p = 0; p < 4; ++p) {
    int rr = r + p * 16;  // dout-local
    bf16x4 o = {(bf16)tile[c4 * 4 + 0][rr], (bf16)tile[c4 * 4 + 1][rr],
                (bf16)tile[c4 * 4 + 2][rr], (bf16)tile[c4 * 4 + 3][rr]};
    *(bf16x4*)&Wt[(size_t)(dout0 + rr) * D_ + din0 + c4 * 4] = o;
  }
}

// ---------------------------------------------------------------------------
// k_wa: wa1 = W @ a1, wa2 = W @ a2 (fp32-exact logits path)
// ---------------------------------------------------------------------------
__global__ __launch_bounds__(256) void k_wa(const float* __restrict__ W,
                                            const float* __restrict__ a1,
                                            const float* __restrict__ a2,
                                            float* __restrict__ wa1,
                                            float* __restrict__ wa2) {
  const int wv = threadIdx.x >> 6, lane = threadIdx.x & 63;
  const int row = blockIdx.x * 4 + wv;
  const float* wr = W + (size_t)row * D_;
  float d1 = 0.f, d2 = 0.f;
#pragma unroll
  for (int p = 0; p < 8; ++p) {
    int c = lane + p * 64;
    float w = wr[c];
    d1 = fmaf(w, a1[c], d1);
    d2 = fmaf(w, a2[c], d2);
  }
#pragma unroll
  for (int off = 32; off > 0; off >>= 1) {
    d1 += __shfl_down(d1, off, 64);
    d2 += __shfl_down(d2, off, 64);
  }
  if (lane == 0) {
    wa1[row] = d1;
    wa2[row] = d2;
  }
}

// ---------------------------------------------------------------------------
// k_conv_scores: Xb = bf16(X); s1 = X.wa1 ; s2 = X.wa2 (fp32; X read once)
// ---------------------------------------------------------------------------
__global__ __launch_bounds__(256) void k_conv_scores(
    const float* __restrict__ X, const float* __restrict__ wa1,
    const float* __restrict__ wa2, bf16* __restrict__ Xb,
    float* __restrict__ s1, float* __restrict__ s2) {
  __shared__ float was1[D_], was2[D_];
  const int t = threadIdx.x;
  for (int c = t; c < D_; c += 256) {
    was1[c] = wa1[c];
    was2[c] = wa2[c];
  }
  __syncthreads();
  const int wv = t >> 6, lane = t & 63;
  const int r = blockIdx.x * 4 + wv;
  const float* x = X + (size_t)r * D_;
  float d1 = 0.f, d2 = 0.f;
#pragma unroll
  for (int p = 0; p < 2; ++p) {
    int c = lane * 4 + p * 256;
    float4 xv = *(const float4*)&x[c];
    bf16x4 xb = {(bf16)xv.x, (bf16)xv.y, (bf16)xv.z, (bf16)xv.w};
    *(bf16x4*)&Xb[(size_t)r * D_ + c] = xb;
    d1 += xv.x * was1[c] + xv.y * was1[c + 1] + xv.z * was1[c + 2] +
          xv.w * was1[c + 3];
    d2 += xv.x * was2[c] + xv.y * was2[c + 1] + xv.z * was2[c + 2] +
          xv.w * was2[c + 3];
  }
#pragma unroll
  for (int off = 32; off > 0; off >>= 1) {
    d1 += __shfl_down(d1, off, 64);
    d2 += __shfl_down(d2, off, 64);
  }
  if (lane == 0) {
    s1[r] = d1;
    s2[r] = d2;
  }
}

// ---------------------------------------------------------------------------
// k_hiddenT: Ht[dout][row] = bf16(sum Wt[dout][din]*Xb[row][din])  (stride HTS)
// 128x128 tile, BK=32, async-DMA double-buffer, 1 barrier/iter (unchanged R6).
// ---------------------------------------------------------------------------
__global__ __launch_bounds__(256, 4) void k_hiddenT(const bf16* __restrict__ Xb,
                                                    const bf16* __restrict__ Wt,
                                                    bf16* __restrict__ Ht) {
  __shared__ bf16 As[2][128 * 32];
  __shared__ bf16 Bs[2][128 * 32];
  const int t = threadIdx.x;
  const int m0 = blockIdx.y * 128;
  const int n0 = blockIdx.x * 128;
  const int lane = t & 63, w = t >> 6;
  const int wm = w >> 1, wn = w & 1;
  const int r31 = lane & 31, half = lane >> 5;

  const char* WtB = (const char*)Wt;
  const char* XbB = (const char*)Xb;

  int srcA[2], srcB[2];
#pragma unroll
  for (int q = 0; q < 2; ++q) {
    int g = (w * 2 + q) * 64 + lane;
    int r = g >> 2, pc = g & 3;
    int c = pc ^ (r & 3) ^ ((r >> 2) & 3);
    srcA[q] = ((m0 + r) * D_ + c * 8) * 2;
    srcB[q] = ((n0 + r) * D_ + c * 8) * 2;
  }

  f32x16 acc[2][2];
#pragma unroll
  for (int i = 0; i < 2; ++i)
#pragma unroll
    for (int j = 0; j < 2; ++j)
#pragma unroll
      for (int r = 0; r < 16; ++r) acc[i][j][r] = 0.f;

#pragma unroll
  for (int q = 0; q < 2; ++q) {
    async_copy16(WtB + srcA[q], (char*)&As[0][0] + (w * 2 + q) * 1024);
    async_copy16(XbB + srcB[q], (char*)&Bs[0][0] + (w * 2 + q) * 1024);
  }

#pragma unroll
  for (int it = 0; it < D_ / 32; ++it) {
    const int cur = it & 1;
    __syncthreads();
    if (it + 1 < D_ / 32) {
      const int koff = (it + 1) * 64;
#pragma unroll
      for (int q = 0; q < 2; ++q) {
        async_copy16(WtB + srcA[q] + koff,
                     (char*)&As[cur ^ 1][0] + (w * 2 + q) * 1024);
        async_copy16(XbB + srcB[q] + koff,
                     (char*)&Bs[cur ^ 1][0] + (w * 2 + q) * 1024);
      }
    }
#pragma unroll
    for (int ks = 0; ks < 2; ++ks) {
      const int ko = ks * 16 + half * 8;
      const int c = ko >> 3;
      int mA = wm * 64 + r31, mB = wm * 64 + 32 + r31;
      int nA = wn * 64 + r31, nB = wn * 64 + 32 + r31;
      int pmA = c ^ (mA & 3) ^ ((mA >> 2) & 3);
      int pmB = c ^ (mB & 3) ^ ((mB >> 2) & 3);
      int pnA = c ^ (nA & 3) ^ ((nA >> 2) & 3);
      int pnB = c ^ (nB & 3) ^ ((nB >> 2) & 3);
      bf16x8 a0 = *(const bf16x8*)((const char*)&As[cur][0] + mA * 64 + pmA * 16);
      bf16x8 a1 = *(const bf16x8*)((const char*)&As[cur][0] + mB * 64 + pmB * 16);
      bf16x8 b0 = *(const bf16x8*)((const char*)&Bs[cur][0] + nA * 64 + pnA * 16);
      bf16x8 b1 = *(const bf16x8*)((const char*)&Bs[cur][0] + nB * 64 + pnB * 16);
      acc[0][0] = __builtin_amdgcn_mfma_f32_32x32x16_bf16(a0, b0, acc[0][0], 0, 0, 0);
      acc[0][1] = __builtin_amdgcn_mfma_f32_32x32x16_bf16(a0, b1, acc[0][1], 0, 0, 0);
      acc[1][0] = __builtin_amdgcn_mfma_f32_32x32x16_bf16(a1, b0, acc[1][0], 0, 0, 0);
      acc[1][1] = __builtin_amdgcn_mfma_f32_32x32x16_bf16(a1, b1, acc[1][1], 0, 0, 0);
    }
  }

#pragma unroll
  for (int mt = 0; mt < 2; ++mt)
#pragma unroll
    for (int r = 0; r < 16; ++r) {
      int m = wm * 64 + mt * 32 + (r & 3) + 8 * (r >> 2) + 4 * half;
#pragma unroll
      for (int nt = 0; nt < 2; ++nt) {
        int n = wn * 64 + nt * 32 + r31;
        Ht[(size_t)(m0 + m) * HTS + n0 + n] = (bf16)acc[mt][nt][r];
      }
    }
}

// ---------------------------------------------------------------------------
// k_attn: out = elu( softmax_row(mask(leaky(s1_i+s2_j))) @ H )
// Block: 64 rows x 512 d (8 waves x 64 d); b = blockIdx&7 -> XCD-pinned so the
// 2 MB Ht batch-slice stays in one XCD's L2. Ps in super-chunks of 256 j
// (2 barriers each, 16 total), graph/s2 reg-prefetched one SC ahead.
// Hs is WAVE-PRIVATE: 2 slots x 32-j sub-chunks, async-DMA'd by the owning
// wave and gated by manual s_waitcnt vmcnt(N) (in-order retirement makes N
// exact: 4 steady-state, 20 when the 16 graph loads sit between). No barrier
// touches the Hs pipeline except at SC boundaries (where DMAs are long done).
// ---------------------------------------------------------------------------
#define JS 256
#define NSC (N_ / JS)  // 8
#define BKh 32
#define NSUB (N_ / BKh)  // 64

__global__ __launch_bounds__(512, 1) void k_attn(const bf16* __restrict__ Ht,
                                                 const int* __restrict__ graph,
                                                 const float* __restrict__ s1,
                                                 const float* __restrict__ s2,
                                                 float* __restrict__ out) {
  __shared__ bf16 Hs[2][D_ * BKh];   // 2 x 32 KB, granule-swizzled
  __shared__ bf16 Ps[64 * JS];       // 32 KB, granule-swizzled (g ^= row&7)
  __shared__ float sum_part[64][8];
  __shared__ float row_sum[64];

  const int t = threadIdx.x;
  const int b = blockIdx.x & 7;            // XCD-pinned batch
  const int i0 = (blockIdx.x >> 3) * 64;   // row tile
  const int lane = t & 63, w = t >> 6;
  const int r31 = lane & 31, half = lane >> 5;
  const int d0 = w * 64;

  const char* HtB = (const char*)(Ht + (size_t)b * N_);
  const int* Gb = graph + ((size_t)b * N_ + i0) * N_;
  const float* s2g = s2 + b * N_;

  const int pi = t >> 3;       // P row 0..63
  const int m8 = t & 7;        // j-block within SC: j = m8*32 + [0,32)
  const float s1r = s1[b * N_ + i0 + pi];
  float rsum = 0.f;

  f32x16 acc[2][2];
#pragma unroll
  for (int i = 0; i < 2; ++i)
#pragma unroll
    for (int j = 0; j < 2; ++j)
#pragma unroll
      for (int r = 0; r < 16; ++r) acc[i][j][r] = 0.f;

  // per-lane DMA source byte offsets (j-independent); d is block-global
  int dsrc[4];
#pragma unroll
  for (int q = 0; q < 4; ++q) {
    int g = (w * 4 + q) * 64 + lane;
    int d = g >> 2, pc = g & 3;
    int c = pc ^ (d & 3) ^ ((d >> 2) & 3);
    dsrc[q] = d * (HTS * 2) + c * 16;
  }

  // prologue: DMA sub-chunks 0,1 ; graph/s2 regs for SC 0
#pragma unroll
  for (int q = 0; q < 4; ++q) {
    async_copy16(HtB + dsrc[q] + 0, (char*)&Hs[0][0] + (w * 4 + q) * 1024);
  }
#pragma unroll
  for (int q = 0; q < 4; ++q) {
    async_copy16(HtB + dsrc[q] + BKh * 2, (char*)&Hs[1][0] + (w * 4 + q) * 1024);
  }
  int4 gg[8];
  float4 ss[8];
#pragma unroll
  for (int u = 0; u < 8; ++u) {
    gg[u] = *(const int4*)&Gb[(size_t)pi * N_ + m8 * 32 + u * 4];
    ss[u] = *(const float4*)&s2g[m8 * 32 + u * 4];
  }

  for (int sc = 0; sc < NSC; ++sc) {
    // compute P values for this SC from prefetched regs
    float pv[32];
#pragma unroll
    for (int u = 0; u < 8; ++u) {
      int gv[4] = {gg[u].x, gg[u].y, gg[u].z, gg[u].w};
      float sv[4] = {ss[u].x, ss[u].y, ss[u].z, ss[u].w};
#pragma unroll
      for (int v = 0; v < 4; ++v) {
        float e = s1r + sv[v];
        e = (e > 0.f) ? e : NEG_ALPHA * e;
        float pe = (gv[v] != 0) ? __expf(e) : 0.f;
        pv[u * 4 + v] = pe;
        rsum += pe;
      }
    }
    __syncthreads();  // previous SC's Ps readers done (drains DMA: complete)
    // store Ps, swizzled granules: pos = g ^ (row&7), row stride 256
#pragma unroll
    for (int u = 0; u < 4; ++u) {
      // granule g = m8*4 + u covers pv[u*8 .. u*8+8) -> j interleave: pv index
      // mapping: pv[q4*4+v] is j = m8*32 + q4*4 + v; granule u holds j-local
      // [u*8, u*8+8) = pv[(2u)*4 .. (2u+1)*4+4)
      bf16x8 pk = {(bf16)pv[u * 8 + 0], (bf16)pv[u * 8 + 1],
                   (bf16)pv[u * 8 + 2], (bf16)pv[u * 8 + 3],
                   (bf16)pv[u * 8 + 4], (bf16)pv[u * 8 + 5],
                   (bf16)pv[u * 8 + 6], (bf16)pv[u * 8 + 7]};
      int g = m8 * 4 + u;
      *(bf16x8*)&Ps[pi * JS + (g ^ (pi & 7)) * 8] = pk;
    }
    __syncthreads();  // Ps visible
#pragma unroll
    for (int s = 0; s < JS / BKh; ++s) {
      const int gsub = sc * 8 + s;
      const int slot = gsub & 1;
      // gate on this slot's DMA (in-order vmcnt retirement):
      if (s == 1 || s == 2) WAITVM20(); else WAITVM4();
      __builtin_amdgcn_sched_barrier(0);
      // MFMA: Ps (A) + wave-private Hs (B)
#pragma unroll
      for (int ks = 0; ks < 2; ++ks) {
        const int kog = s * 32 + ks * 16 + half * 8;  // j within SC
        const int gA = kog >> 3;                      // Ps granule 0..31
        const int cB = (ks * 16 + half * 8) >> 3;     // Hs granule 0..3
        int dA = d0 + r31, dB = d0 + 32 + r31;
        int pA = cB ^ (dA & 3) ^ ((dA >> 2) & 3);
        int pB = cB ^ (dB & 3) ^ ((dB >> 2) & 3);
        bf16x8 a0 = *(const bf16x8*)&Ps[r31 * JS + (gA ^ (r31 & 7)) * 8];
        bf16x8 a1 = *(const bf16x8*)&Ps[(32 + r31) * JS + (gA ^ ((32 + r31) & 7)) * 8];
        bf16x8 b0 = *(const bf16x8*)((const char*)&Hs[slot][0] + dA * 64 + pA * 16);
        bf16x8 b1 = *(const bf16x8*)((const char*)&Hs[slot][0] + dB * 64 + pB * 16);
        acc[0][0] = __builtin_amdgcn_mfma_f32_32x32x16_bf16(a0, b0, acc[0][0], 0, 0, 0);
        acc[0][1] = __builtin_amdgcn_mfma_f32_32x32x16_bf16(a0, b1, acc[0][1], 0, 0, 0);
        acc[1][0] = __builtin_amdgcn_mfma_f32_32x32x16_bf16(a1, b0, acc[1][0], 0, 0, 0);
        acc[1][1] = __builtin_amdgcn_mfma_f32_32x32x16_bf16(a1, b1, acc[1][1], 0, 0, 0);
      }
      // refill pipeline: DMA sub-chunk gsub+2 into this slot
      if (gsub + 2 < NSUB) {
        const int joff = (gsub + 2) * BKh * 2;
#pragma unroll
        for (int q = 0; q < 4; ++q)
          async_copy16(HtB + dsrc[q] + joff,
                       (char*)&Hs[slot][0] + (w * 4 + q) * 1024);
      }
      // graph/s2 prefetch for next SC (issued once, after the DMAs)
      if (s == 0 && sc + 1 < NSC) {
#pragma unroll
        for (int u = 0; u < 8; ++u) {
          gg[u] = *(const int4*)&Gb[(size_t)pi * N_ + (sc + 1) * JS + m8 * 32 + u * 4];
          ss[u] = *(const float4*)&s2g[(sc + 1) * JS + m8 * 32 + u * 4];
        }
      }
    }
  }

  // row sums
  sum_part[pi][m8] = rsum;
  __syncthreads();
  if (t < 64) {
    float s = 0.f;
#pragma unroll
    for (int k = 0; k < 8; ++k) s += sum_part[t][k];
    row_sum[t] = s;
  }
  __syncthreads();

  // epilogue: normalize + elu + store (C/D 32x32: col=lane&31,
  // row=(r&3)+8*(r>>2)+4*half)
#pragma unroll
  for (int mt = 0; mt < 2; ++mt) {
    float inv[16];
#pragma unroll
    for (int r = 0; r < 16; ++r)
      inv[r] = 1.f / row_sum[mt * 32 + (r & 3) + 8 * (r >> 2) + 4 * half];
#pragma unroll
    for (int nt = 0; nt < 2; ++nt) {
      const int d = d0 + nt * 32 + r31;
#pragma unroll
      for (int r = 0; r < 16; ++r) {
        int i = mt * 32 + (r & 3) + 8 * (r >> 2) + 4 * half;
        float x = acc[mt][nt][r] * inv[r];
        out[((size_t)b * N_ + i0 + i) * D_ + d] = (x > 0.f) ? x : expm1f(x);
      }
    }
  }
}

// ---------------------------------------------------------------------------
extern "C" void kernel_launch(void* const* d_in, const int* in_sizes, int n_in,
                              void* d_out, int out_size, void* d_ws,
                              size_t ws_size, hipStream_t stream) {
  const float* X = (const float*)d_in[0];
  const int* graph = (const int*)d_in[1];
  const float* W = (const float*)d_in[2];
  const float* a1 = (const float*)d_in[3];
  const float* a2 = (const float*)d_in[4];
  float* out = (float*)d_out;

  char* ws = (char*)d_ws;
  bf16* Wt = (bf16*)ws;                  // 512 KB
  bf16* Ht = (bf16*)(ws + (1 << 19));    // 512*HTS*2 = 16,809,984 B
  bf16* Xb = (bf16*)(ws + 17334272);     // 16 MB
  float* s1 = (float*)(ws + 34111488);
  float* s2 = (float*)(ws + 34177024);
  float* wa1 = (float*)(ws + 34242560);
  float* wa2 = (float*)(ws + 34244608);

  hipLaunchKernelGGL(k_prep, dim3(64), dim3(256), 0, stream, W, Wt);
  hipLaunchKernelGGL(k_wa, dim3(128), dim3(256), 0, stream, W, a1, a2, wa1, wa2);
  hipLaunchKernelGGL(k_conv_scores, dim3(NROWS / 4), dim3(256), 0, stream, X,
                     wa1, wa2, Xb, s1, s2);
  hipLaunchKernelGGL(k_hiddenT, dim3(NROWS / 128, D_ / 128), dim3(256), 0,
                     stream, Xb, Wt, Ht);
  hipLaunchKernelGGL(k_attn, dim3(256), dim3(512), 0, stream, Ht, graph, s1,
                     s2, out);
}